// Round 4
// baseline (378.270 us; speedup 1.0000x reference)
//
#include <hip/hip_runtime.h>
#include <stdint.h>

typedef __bf16 bf16_t;
typedef bf16_t bf16x8 __attribute__((ext_vector_type(8)));
typedef float f32x4 __attribute__((ext_vector_type(4)));
typedef unsigned short u16x8 __attribute__((ext_vector_type(8)));

#define KDIM 512

__device__ __forceinline__ unsigned short f2bf(float f) {
  unsigned int u = __float_as_uint(f);
  u = (u + 0x7FFFu + ((u >> 16) & 1u)) >> 16;
  return (unsigned short)u;
}

// ================= merged fp32->bf16 conversion (5 segments, 8 elems/thread) =================
struct CvtArgs {
  const float *s0, *s1, *s2, *s3, *s4;
  unsigned short *d0, *d1, *d2, *d3, *d4;
};
__device__ __forceinline__ void cvt8(const float* s, unsigned short* d, int i) {
  const float4* sp = (const float4*)s;
  float4 a = sp[2 * (size_t)i], b = sp[2 * (size_t)i + 1];
  u16x8 r;
  r[0] = f2bf(a.x); r[1] = f2bf(a.y); r[2] = f2bf(a.z); r[3] = f2bf(a.w);
  r[4] = f2bf(b.x); r[5] = f2bf(b.y); r[6] = f2bf(b.z); r[7] = f2bf(b.w);
  *(u16x8*)(d + (size_t)8 * i) = r;
}
__global__ void cvt_multi(CvtArgs a) {
  int i = blockIdx.x * blockDim.x + threadIdx.x;
  if (i < 688128)       cvt8(a.s0, a.d0, i);
  else if (i < 1032192) cvt8(a.s1, a.d1, i - 688128);
  else if (i < 1261568) cvt8(a.s2, a.d2, i - 1032192);
  else if (i < 1376256) cvt8(a.s3, a.d3, i - 1261568);
  else                  cvt8(a.s4, a.d4, i - 1376256);
}

// ================= merged transpose+cvt: W[p*512,512] fp32 -> WtB[p][512 d][512 e] bf16 =========
struct TpArgs {
  const float *w0, *w1, *w2, *w3;
  unsigned short *t0, *t1, *t2, *t3;
};
__global__ __launch_bounds__(256) void transpose_all(TpArgs a) {
  __shared__ float tile[64][65];
  int bid = blockIdx.x;
  int e, base, P;
  if (bid < 256)       { e = 0; base = 0;    P = 4; }
  else if (bid < 768)  { e = 1; base = 256;  P = 8; }
  else if (bid < 1536) { e = 2; base = 768;  P = 12; }
  else                 { e = 3; base = 1536; P = 24; }
  const float* W = e == 0 ? a.w0 : e == 1 ? a.w1 : e == 2 ? a.w2 : a.w3;
  unsigned short* Wt = e == 0 ? a.t0 : e == 1 ? a.t1 : e == 2 ? a.t2 : a.t3;
  int r = bid - base;
  int qb = r % (P * 8), db = r / (P * 8);
  int q0 = qb * 64, d0 = db * 64;
  int t = threadIdx.x;
  int c = t & 63, r4 = t >> 6;
#pragma unroll
  for (int i = 0; i < 16; ++i) {
    int row = r4 + i * 4;
    tile[row][c] = W[(size_t)(q0 + row) * 512 + d0 + c];
  }
  __syncthreads();
  int j = q0 >> 9, e0 = q0 & 511;
  size_t obase = (size_t)j * 262144 + (size_t)d0 * 512 + e0;
#pragma unroll
  for (int i = 0; i < 16; ++i) {
    int dd = r4 + i * 4;
    Wt[obase + (size_t)dd * 512 + c] = f2bf(tile[c][dd]);
  }
}

// ================= merged fused bias: bf[jg*512+o] = Wp[o,:]@b_e[jl*512:]+bp[o] ================
struct BiasArgs { const float *b0, *b1, *b2, *b3; };
__global__ void bias_all(const float* __restrict__ Wp, BiasArgs a,
                         const float* __restrict__ bp, float* __restrict__ bf) {
  int jg = blockIdx.x;  // 0..47
  int e, base;
  if (jg < 4)       { e = 0; base = 0; }
  else if (jg < 12) { e = 1; base = 4; }
  else if (jg < 24) { e = 2; base = 12; }
  else              { e = 3; base = 24; }
  const float* b = e == 0 ? a.b0 : e == 1 ? a.b1 : e == 2 ? a.b2 : a.b3;
  int jl = jg - base;
  for (int o = threadIdx.x; o < 512; o += blockDim.x) {
    float s = bp[o];
    const float* wr = Wp + (size_t)o * 512;
    const float* br = b + (size_t)jl * 512;
    for (int ee = 0; ee < 512; ++ee) s += wr[ee] * br[ee];
    bf[(size_t)jg * 512 + o] = s;
  }
}

// ================= async global->LDS helpers ==================================================
__device__ __forceinline__ void gload_lds16(const unsigned short* g, unsigned short* l) {
  __builtin_amdgcn_global_load_lds(
      (const __attribute__((address_space(1))) void*)g,
      (__attribute__((address_space(3))) void*)l, 16, 0, 0);
}

// --- 128x64 tile staging for the legacy 128^2 path (fuse_all) ---
__device__ __forceinline__ void stage_tile(const unsigned short* __restrict__ gbase,
                                           unsigned short* lds, int tid) {
#pragma unroll
  for (int i = 0; i < 4; ++i) {
    int lin = i * 4096 + tid * 16;
    int row = lin >> 7;
    int colb = lin & 127;
    int scolb = colb ^ ((row & 7) << 4);
    gload_lds16(gbase + (size_t)row * KDIM + (scolb >> 1), lds + (lin >> 1));
  }
}

// ================= legacy 2-phase 128x128 core (used by fuse_all only) ========================
__device__ __forceinline__ void gemm_dbuf_k512(
    const unsigned short* __restrict__ Ag, const unsigned short* __restrict__ Bg,
    unsigned short* lds, int tid, f32x4 acc[4][4]) {
  int lane = tid & 63;
  int w = tid >> 6;
  int wr0 = (w >> 1) * 64, wc0 = (w & 1) * 64;
  stage_tile(Ag, lds, tid);
  stage_tile(Bg, lds + 8192, tid);
  __syncthreads();
#pragma unroll
  for (int kt = 0; kt < 8; ++kt) {
    unsigned short* curA = lds + ((kt & 1) ? 16384 : 0);
    unsigned short* curB = lds + ((kt & 1) ? 24576 : 8192);
    if (kt < 7) {
      unsigned short* nxtA = lds + ((kt & 1) ? 0 : 16384);
      unsigned short* nxtB = lds + ((kt & 1) ? 8192 : 24576);
      stage_tile(Ag + (kt + 1) * 64, nxtA, tid);
      stage_tile(Bg + (kt + 1) * 64, nxtB, tid);
    }
#pragma unroll
    for (int kk = 0; kk < 2; ++kk) {
      bf16x8 av[4], bv[4];
      int cb = kk * 64 + (lane >> 4) * 16;
#pragma unroll
      for (int f = 0; f < 4; ++f) {
        int ra = wr0 + f * 16 + (lane & 15);
        av[f] = *(const bf16x8*)((const char*)curA + ra * 128 + (cb ^ ((ra & 7) << 4)));
        int rb = wc0 + f * 16 + (lane & 15);
        bv[f] = *(const bf16x8*)((const char*)curB + rb * 128 + (cb ^ ((rb & 7) << 4)));
      }
#pragma unroll
      for (int fi = 0; fi < 4; ++fi)
#pragma unroll
        for (int fj = 0; fj < 4; ++fj)
          acc[fi][fj] = __builtin_amdgcn_mfma_f32_16x16x32_bf16(av[fi], bv[fj], acc[fi][fj], 0, 0, 0);
    }
    __syncthreads();
  }
}

// ================= merged weight-fuse GEMM (128^2 path) =======================================
struct FuseArgs {
  const unsigned short *wt0, *wt1, *wt2, *wt3;
  unsigned short *wf0, *wf1, *wf2, *wf3;
};
__global__ __launch_bounds__(256) void fuse_all(const unsigned short* __restrict__ Wpb, FuseArgs a) {
  __shared__ unsigned short lds[32768];
  int bid = blockIdx.x;
  int e, base, P;
  if (bid < 64)       { e = 0; base = 0;   P = 4; }
  else if (bid < 192) { e = 1; base = 64;  P = 8; }
  else if (bid < 384) { e = 2; base = 192; P = 12; }
  else                { e = 3; base = 384; P = 24; }
  const unsigned short* WtB = e == 0 ? a.wt0 : e == 1 ? a.wt1 : e == 2 ? a.wt2 : a.wt3;
  unsigned short* Wf = e == 0 ? a.wf0 : e == 1 ? a.wf1 : e == 2 ? a.wf2 : a.wf3;
  int r = bid - base;
  int tileM = r % (4 * P), tileN = r / (4 * P);
  int tid = threadIdx.x;
  int lane = tid & 63, w = tid >> 6;
  int wr0 = (w >> 1) * 64, wc0 = (w & 1) * 64;
  int j = (tileM * 128) >> 9;
  const unsigned short* Ag = Wpb + (size_t)((tileM * 128) & 511) * 512;
  const unsigned short* Bg = WtB + (size_t)j * 262144 + (size_t)(tileN * 128) * 512;
  f32x4 acc[4][4] = {};
  gemm_dbuf_k512(Ag, Bg, lds, tid, acc);
#pragma unroll
  for (int fi = 0; fi < 4; ++fi)
#pragma unroll
    for (int fj = 0; fj < 4; ++fj) {
      int col = tileN * 128 + wc0 + fj * 16 + (lane & 15);
#pragma unroll
      for (int r2 = 0; r2 < 4; ++r2) {
        int m = tileM * 128 + wr0 + fi * 16 + (lane >> 4) * 4 + r2;
        Wf[(size_t)m * 512 + col] = f2bf(acc[fi][fj][r2]);
      }
    }
}

// ================= 256x256 / BK=32 / 4-slot counted-vmcnt pipelined core ======================
// 512 threads = 8 waves (2M x 4N); per-wave 128x64 output -> acc[8][4].
// LDS: 4 slots x (A 16KB + B 16KB) = 128 KiB. Slot s%4 holds K-tile s (32 k).
// Stage K-tile s+3 during compute of s (slot reuse distance 4 => race-free).
// Boundary: s_waitcnt vmcnt(8) (2 K-tiles in flight) + s_barrier, in ONE asm (memory clobber).
#define SLOT_BYTES 32768
#define B_OFF 16384

// stage one operand's K-tile: 256 rows x 32 cols bf16 = 16 KB; 2 gloads x 16B per thread.
// LDS dest linear; global source pre-swizzled: chunk c = cs ^ ((row>>1)&3)  (rule #21).
__device__ __forceinline__ void stage_op32(const unsigned short* __restrict__ gbase,
                                           char* ldsOp, int tid, int kt) {
  int rlo = tid >> 2;
  int c = (tid & 3) ^ ((tid >> 3) & 3);
#pragma unroll
  for (int i = 0; i < 2; ++i) {
    int row = i * 128 + rlo;
    gload_lds16(gbase + (size_t)row * KDIM + kt * 32 + c * 8,
                (unsigned short*)(ldsOp + i * 8192 + tid * 16));
  }
}

// swizzled fragment read: global chunk c of row r lives at slot (c ^ ((r>>1)&3))
__device__ __forceinline__ bf16x8 lds_frag(const char* op, int r, int c) {
  return *(const bf16x8*)(op + r * 64 + ((c ^ ((r >> 1) & 3)) << 4));
}

__device__ __forceinline__ void gemm256_k512(
    const unsigned short* __restrict__ Ag, const unsigned short* __restrict__ Bg,
    char* lds, int tid, f32x4 acc[8][4]) {
  int lane = tid & 63, w = tid >> 6;
  int wr = w >> 2, wc = w & 3;
  int c16 = lane >> 4, rl = lane & 15;
  // prologue: stage K-tiles 0,1,2 into slots 0,1,2 (12 gloads/thread... 3x4)
#pragma unroll
  for (int s = 0; s < 3; ++s) {
    stage_op32(Ag, lds + s * SLOT_BYTES, tid, s);
    stage_op32(Bg, lds + s * SLOT_BYTES + B_OFF, tid, s);
  }
  for (int s = 0; s < 16; ++s) {
    // ledger: outstanding after K-tile s's loads = K-tiles {s+1, s+2} = 8 gloads (4 each)
    if (s <= 13)      asm volatile("s_waitcnt vmcnt(8)\n\ts_barrier" ::: "memory");
    else if (s == 14) asm volatile("s_waitcnt vmcnt(4)\n\ts_barrier" ::: "memory");
    else              asm volatile("s_waitcnt vmcnt(0)\n\ts_barrier" ::: "memory");
    const char* As = lds + (s & 3) * SLOT_BYTES;
    const char* Bs = As + B_OFF;
    char* nslot = lds + ((s + 3) & 3) * SLOT_BYTES;
    bool more = (s + 3) < 16;
    // ---- phase 0: stage A(s+3); read bv[0..3] + av[0..3]; 16 MFMA ----
    if (more) stage_op32(Ag, nslot, tid, s + 3);
    bf16x8 bv[4];
#pragma unroll
    for (int fj = 0; fj < 4; ++fj)
      bv[fj] = lds_frag(Bs, wc * 64 + fj * 16 + rl, c16);
    bf16x8 av[4];
#pragma unroll
    for (int fi = 0; fi < 4; ++fi)
      av[fi] = lds_frag(As, wr * 128 + fi * 16 + rl, c16);
    __builtin_amdgcn_s_setprio(1);
#pragma unroll
    for (int fi = 0; fi < 4; ++fi)
#pragma unroll
      for (int fj = 0; fj < 4; ++fj)
        acc[fi][fj] = __builtin_amdgcn_mfma_f32_16x16x32_bf16(av[fi], bv[fj], acc[fi][fj], 0, 0, 0);
    __builtin_amdgcn_s_setprio(0);
    asm volatile("s_barrier" ::: "memory");
    // ---- phase 1: stage B(s+3); read av[4..7]; 16 MFMA ----
    if (more) stage_op32(Bg, nslot + B_OFF, tid, s + 3);
#pragma unroll
    for (int fi = 0; fi < 4; ++fi)
      av[fi] = lds_frag(As, wr * 128 + (4 + fi) * 16 + rl, c16);
    __builtin_amdgcn_s_setprio(1);
#pragma unroll
    for (int fi = 0; fi < 4; ++fi)
#pragma unroll
      for (int fj = 0; fj < 4; ++fj)
        acc[4 + fi][fj] = __builtin_amdgcn_mfma_f32_16x16x32_bf16(av[fi], bv[fj], acc[4 + fi][fj], 0, 0, 0);
    __builtin_amdgcn_s_setprio(0);
  }
}

// ================= fused expert GEMM (256^2) + gate + scatter-combine =========================
// First-writer per batch is static: b%4==3 -> expert 0, else expert b%4.  Plain RMW is
// race-free: one touch per element per kernel; the 4 expert kernels are stream-serialized.
// (Do NOT merge these launches: store/add ordering relies on stream serialization.)
template <int L, int P, int EXPERT>
__global__ __launch_bounds__(512, 2) void expert_fused256(
    const unsigned short* __restrict__ A,   // x bf16 [128*L, 512]
    const unsigned short* __restrict__ Wf,  // [P*512, 512] bf16
    const float* __restrict__ bf,           // [P*512]
    const float* __restrict__ gates, const int* __restrict__ bidx,
    const int* __restrict__ eidx, float* __restrict__ out, int ebase) {
  __shared__ char lds[131072];
  int tid = threadIdx.x;
  int lane = tid & 63, w = tid >> 6;
  int wr = w >> 2, wc = w & 3;
  int tileM = blockIdx.x, tileN = blockIdx.y;
  const unsigned short* Ag = A + (size_t)tileM * 256 * KDIM;
  const unsigned short* Bg = Wf + (size_t)tileN * 256 * KDIM;
  f32x4 acc[8][4] = {};
  gemm256_k512(Ag, Bg, lds, tid, acc);

  int j = tileN >> 1;                        // 256-col tile stays within one 512-col j-group
  int ob = (tileN & 1) * 256 + wc * 64;
  float bv[4];
  int ocol[4];
#pragma unroll
  for (int fj = 0; fj < 4; ++fj) {
    ocol[fj] = ob + fj * 16 + (lane & 15);
    bv[fj] = bf[(j << 9) + ocol[fj]];
  }
#pragma unroll
  for (int fi = 0; fi < 8; ++fi) {
    int m0 = tileM * 256 + wr * 128 + fi * 16 + (lane >> 4) * 4;
    int n = m0 / L, li = m0 % L;
    int b = bidx[ebase + n];
    float g = gates[b * 4 + eidx[ebase + n]];
#pragma unroll
    for (int r = 0; r < 4; ++r) {
      if (li == L) { li = 0; ++n; b = bidx[ebase + n]; g = gates[b * 4 + eidx[ebase + n]]; }
      int t = li * P + j;
      float* orow = out + ((size_t)b * 336 + t) * 512;
      int bm4 = b & 3;
      bool first = (bm4 == 3) ? (EXPERT == 0) : (bm4 == EXPERT);
#pragma unroll
      for (int fj = 0; fj < 4; ++fj) {
        float v = g * (acc[fi][fj][r] + bv[fj]);
        if (first) orow[ocol[fj]] = v;
        else       orow[ocol[fj]] += v;
      }
      ++li;
    }
  }
}

extern "C" void kernel_launch(void* const* d_in, const int* in_sizes, int n_in,
                              void* d_out, int out_size, void* d_ws, size_t ws_size,
                              hipStream_t stream) {
  const float* xs[4]   = {(const float*)d_in[0], (const float*)d_in[3], (const float*)d_in[6], (const float*)d_in[9]};
  const float* Wfp[4]  = {(const float*)d_in[1], (const float*)d_in[4], (const float*)d_in[7], (const float*)d_in[10]};
  const float* bias[4] = {(const float*)d_in[2], (const float*)d_in[5], (const float*)d_in[8], (const float*)d_in[11]};
  const float* gates = (const float*)d_in[12];
  const float* Wp    = (const float*)d_in[13];
  const float* bp    = (const float*)d_in[14];
  const int* bidx    = (const int*)d_in[15];
  const int* eidx    = (const int*)d_in[16];

  static const int xs_elems[4] = {5505024, 2752512, 1835008, 917504};
  static const int W_elems[4]  = {1048576, 2097152, 3145728, 6291456};

  unsigned short* w = (unsigned short*)d_ws;
  size_t off = 0;
  unsigned short* xsb[4]; unsigned short* WtB[4]; unsigned short* Wfb[4];
  for (int i = 0; i < 4; i++) { xsb[i] = w + off; off += xs_elems[i]; }
  for (int i = 0; i < 4; i++) { WtB[i] = w + off; off += W_elems[i]; }
  for (int i = 0; i < 4; i++) { Wfb[i] = w + off; off += W_elems[i]; }
  unsigned short* Wpb = w + off; off += 262144;
  float* bfused = (float*)(w + off);  // 48*512 floats

  // --- prep: 4 launches ---
  CvtArgs ca = {xs[0], xs[1], xs[2], xs[3], Wp, xsb[0], xsb[1], xsb[2], xsb[3], Wpb};
  cvt_multi<<<5504, 256, 0, stream>>>(ca);

  TpArgs ta = {Wfp[0], Wfp[1], Wfp[2], Wfp[3], WtB[0], WtB[1], WtB[2], WtB[3]};
  transpose_all<<<3072, 256, 0, stream>>>(ta);

  FuseArgs fa = {WtB[0], WtB[1], WtB[2], WtB[3], Wfb[0], Wfb[1], Wfb[2], Wfb[3]};
  fuse_all<<<768, 256, 0, stream>>>(Wpb, fa);

  BiasArgs ba = {bias[0], bias[1], bias[2], bias[3]};
  bias_all<<<48, 256, 0, stream>>>(Wp, ba, bp, bfused);

  // --- fused expert GEMM (256^2 pipelined) + gated scatter-combine ---
  expert_fused256<84, 4, 0><<<dim3(42, 8),  512, 0, stream>>>(xsb[0], Wfb[0], bfused + 0 * 512,  gates, bidx, eidx, (float*)d_out, 0);
  expert_fused256<42, 8, 1><<<dim3(21, 16), 512, 0, stream>>>(xsb[1], Wfb[1], bfused + 4 * 512,  gates, bidx, eidx, (float*)d_out, 128);
  expert_fused256<28, 12, 2><<<dim3(14, 24), 512, 0, stream>>>(xsb[2], Wfb[2], bfused + 12 * 512, gates, bidx, eidx, (float*)d_out, 256);
  expert_fused256<14, 24, 3><<<dim3(7, 48),  512, 0, stream>>>(xsb[3], Wfb[3], bfused + 24 * 512, gates, bidx, eidx, (float*)d_out, 384);
}

// Round 6
// 273.582 us; speedup vs baseline: 1.3827x; 1.3827x over previous
//
#include <hip/hip_runtime.h>
#include <stdint.h>

typedef __bf16 bf16_t;
typedef bf16_t bf16x8 __attribute__((ext_vector_type(8)));
typedef float f32x4 __attribute__((ext_vector_type(4)));
typedef unsigned short u16x8 __attribute__((ext_vector_type(8)));

#define KDIM 512

__device__ __forceinline__ unsigned short f2bf(float f) {
  unsigned int u = __float_as_uint(f);
  u = (u + 0x7FFFu + ((u >> 16) & 1u)) >> 16;
  return (unsigned short)u;
}

// ================= merged fp32->bf16 conversion (5 segments, 8 elems/thread) =================
struct CvtArgs {
  const float *s0, *s1, *s2, *s3, *s4;
  unsigned short *d0, *d1, *d2, *d3, *d4;
};
__device__ __forceinline__ void cvt8(const float* s, unsigned short* d, int i) {
  const float4* sp = (const float4*)s;
  float4 a = sp[2 * (size_t)i], b = sp[2 * (size_t)i + 1];
  u16x8 r;
  r[0] = f2bf(a.x); r[1] = f2bf(a.y); r[2] = f2bf(a.z); r[3] = f2bf(a.w);
  r[4] = f2bf(b.x); r[5] = f2bf(b.y); r[6] = f2bf(b.z); r[7] = f2bf(b.w);
  *(u16x8*)(d + (size_t)8 * i) = r;
}
__global__ void cvt_multi(CvtArgs a) {
  int i = blockIdx.x * blockDim.x + threadIdx.x;
  if (i < 688128)       cvt8(a.s0, a.d0, i);
  else if (i < 1032192) cvt8(a.s1, a.d1, i - 688128);
  else if (i < 1261568) cvt8(a.s2, a.d2, i - 1032192);
  else if (i < 1376256) cvt8(a.s3, a.d3, i - 1261568);
  else                  cvt8(a.s4, a.d4, i - 1376256);
}

// ================= merged transpose+cvt: W[p*512,512] fp32 -> WtB[p][512 d][512 e] bf16 =========
struct TpArgs {
  const float *w0, *w1, *w2, *w3;
  unsigned short *t0, *t1, *t2, *t3;
};
__global__ __launch_bounds__(256) void transpose_all(TpArgs a) {
  __shared__ float tile[64][65];
  int bid = blockIdx.x;
  int e, base, P;
  if (bid < 256)       { e = 0; base = 0;    P = 4; }
  else if (bid < 768)  { e = 1; base = 256;  P = 8; }
  else if (bid < 1536) { e = 2; base = 768;  P = 12; }
  else                 { e = 3; base = 1536; P = 24; }
  const float* W = e == 0 ? a.w0 : e == 1 ? a.w1 : e == 2 ? a.w2 : a.w3;
  unsigned short* Wt = e == 0 ? a.t0 : e == 1 ? a.t1 : e == 2 ? a.t2 : a.t3;
  int r = bid - base;
  int qb = r % (P * 8), db = r / (P * 8);
  int q0 = qb * 64, d0 = db * 64;
  int t = threadIdx.x;
  int c = t & 63, r4 = t >> 6;
#pragma unroll
  for (int i = 0; i < 16; ++i) {
    int row = r4 + i * 4;
    tile[row][c] = W[(size_t)(q0 + row) * 512 + d0 + c];
  }
  __syncthreads();
  int j = q0 >> 9, e0 = q0 & 511;
  size_t obase = (size_t)j * 262144 + (size_t)d0 * 512 + e0;
#pragma unroll
  for (int i = 0; i < 16; ++i) {
    int dd = r4 + i * 4;
    Wt[obase + (size_t)dd * 512 + c] = f2bf(tile[c][dd]);
  }
}

// ================= merged fused bias: bf[jg*512+o] = Wp[o,:]@b_e[jl*512:]+bp[o] ================
struct BiasArgs { const float *b0, *b1, *b2, *b3; };
__global__ void bias_all(const float* __restrict__ Wp, BiasArgs a,
                         const float* __restrict__ bp, float* __restrict__ bf) {
  int jg = blockIdx.x;  // 0..47
  int e, base;
  if (jg < 4)       { e = 0; base = 0; }
  else if (jg < 12) { e = 1; base = 4; }
  else if (jg < 24) { e = 2; base = 12; }
  else              { e = 3; base = 24; }
  const float* b = e == 0 ? a.b0 : e == 1 ? a.b1 : e == 2 ? a.b2 : a.b3;
  int jl = jg - base;
  for (int o = threadIdx.x; o < 512; o += blockDim.x) {
    float s = bp[o];
    const float* wr = Wp + (size_t)o * 512;
    const float* br = b + (size_t)jl * 512;
    for (int ee = 0; ee < 512; ++ee) s += wr[ee] * br[ee];
    bf[(size_t)jg * 512 + o] = s;
  }
}

// ================= async global->LDS helpers ==================================================
__device__ __forceinline__ void gload_lds16(const unsigned short* g, unsigned short* l) {
  __builtin_amdgcn_global_load_lds(
      (const __attribute__((address_space(1))) void*)g,
      (__attribute__((address_space(3))) void*)l, 16, 0, 0);
}

// ---- stage a 128x32 bf16 tile (8 KB): LDS dest linear, global source chunk-swizzled ----
// LDS slot (row, sc) holds global 16B-chunk (sc ^ ((row>>1)&3)) of that row (rule #21).
__device__ __forceinline__ void stage32(const unsigned short* __restrict__ g,
                                        char* ldsOp, int tid, int kt) {
  int rlo = tid >> 2;
  int c = (tid & 3) ^ ((tid >> 3) & 3);
#pragma unroll
  for (int i = 0; i < 2; ++i) {
    int row = i * 64 + rlo;
    gload_lds16(g + (size_t)row * KDIM + kt * 32 + c * 8,
                (unsigned short*)(ldsOp + i * 4096 + tid * 16));
  }
}
// swizzled fragment read: global chunk c16 of row r lives at slot (c16 ^ ((r>>1)&3))
__device__ __forceinline__ bf16x8 lds_frag32(const char* op, int r, int c16) {
  return *(const bf16x8*)(op + r * 64 + ((c16 ^ ((r >> 1) & 3)) << 4));
}

// ================= 128x128 bf16 MFMA core, BK=32 double-buffered, 32 KiB LDS ==================
// 256 threads = 4 waves (2x2); per-wave 64x64 -> acc[4][4]. 3 blocks/CU (12 waves) for TLP.
// Buffers: buf b at lds + b*16384; A at +0, B at +8192.
__device__ __forceinline__ void gemm128_k512(
    const unsigned short* __restrict__ Ag, const unsigned short* __restrict__ Bg,
    char* lds, int tid, f32x4 acc[4][4]) {
  int lane = tid & 63, w = tid >> 6;
  int wr0 = (w >> 1) * 64, wc0 = (w & 1) * 64;
  int c16 = lane >> 4, rl = lane & 15;
  stage32(Ag, lds, tid, 0);
  stage32(Bg, lds + 8192, tid, 0);
  __syncthreads();
#pragma unroll
  for (int kt = 0; kt < 16; ++kt) {
    char* cur = lds + (kt & 1) * 16384;
    char* nxt = lds + (((kt & 1) ^ 1)) * 16384;
    if (kt < 15) {  // prefetch next K-tile into the other buffer (overlaps MFMA below)
      stage32(Ag, nxt, tid, kt + 1);
      stage32(Bg, nxt + 8192, tid, kt + 1);
    }
    bf16x8 av[4], bv[4];
#pragma unroll
    for (int f = 0; f < 4; ++f) {
      av[f] = lds_frag32(cur, wr0 + f * 16 + rl, c16);
      bv[f] = lds_frag32(cur + 8192, wc0 + f * 16 + rl, c16);
    }
#pragma unroll
    for (int fi = 0; fi < 4; ++fi)
#pragma unroll
      for (int fj = 0; fj < 4; ++fj)
        acc[fi][fj] = __builtin_amdgcn_mfma_f32_16x16x32_bf16(av[fi], bv[fj], acc[fi][fj], 0, 0, 0);
    __syncthreads();  // drains prefetch (vmcnt) + orders buffer swap; 3-block TLP hides it
  }
}

// ================= merged weight-fuse GEMM: Wf[(j,o),d] = sum_e Wp[o,e]*WtB[j][d][e] ===========
struct FuseArgs {
  const unsigned short *wt0, *wt1, *wt2, *wt3;
  unsigned short *wf0, *wf1, *wf2, *wf3;
};
__global__ __launch_bounds__(256, 3) void fuse_all(const unsigned short* __restrict__ Wpb, FuseArgs a) {
  __shared__ __align__(16) char lds[32768];
  int bid = blockIdx.x;
  int e, base, P;
  if (bid < 64)       { e = 0; base = 0;   P = 4; }
  else if (bid < 192) { e = 1; base = 64;  P = 8; }
  else if (bid < 384) { e = 2; base = 192; P = 12; }
  else                { e = 3; base = 384; P = 24; }
  const unsigned short* WtB = e == 0 ? a.wt0 : e == 1 ? a.wt1 : e == 2 ? a.wt2 : a.wt3;
  unsigned short* Wf = e == 0 ? a.wf0 : e == 1 ? a.wf1 : e == 2 ? a.wf2 : a.wf3;
  int r = bid - base;
  int tileM = r % (4 * P), tileN = r / (4 * P);
  int tid = threadIdx.x;
  int lane = tid & 63, w = tid >> 6;
  int wr0 = (w >> 1) * 64, wc0 = (w & 1) * 64;
  int j = (tileM * 128) >> 9;
  const unsigned short* Ag = Wpb + (size_t)((tileM * 128) & 511) * 512;
  const unsigned short* Bg = WtB + (size_t)j * 262144 + (size_t)(tileN * 128) * 512;
  f32x4 acc[4][4] = {};
  gemm128_k512(Ag, Bg, lds, tid, acc);
#pragma unroll
  for (int fi = 0; fi < 4; ++fi)
#pragma unroll
    for (int fj = 0; fj < 4; ++fj) {
      int col = tileN * 128 + wc0 + fj * 16 + (lane & 15);
#pragma unroll
      for (int r2 = 0; r2 < 4; ++r2) {
        int m = tileM * 128 + wr0 + fi * 16 + (lane >> 4) * 4 + r2;
        Wf[(size_t)m * 512 + col] = f2bf(acc[fi][fj][r2]);
      }
    }
}

// ================= fused expert GEMM + gate + scatter-combine (4 serialized launches) ==========
// Routing: batch b -> experts {b%4, (b+1)%4}; first writer = min of the pair:
//   b%4==0 -> E0, 1 -> E1, 2 -> E2, 3 -> E0.
// => E0 always stores; E1 first iff b%4==1; E2 first iff b%4==2; E3 NEVER first (pure RMW).
// Plain RMW is race-free: one touch per element per kernel; the 4 expert kernels are
// stream-serialized.  (Do NOT merge these launches.)
// XCD-chunked swizzle: xcd = bid&7 owns a contiguous slice of the LARGER-operand tile dim
// x full range of the other -> per-XCD working set (~3-4.5 MB) stays L2-resident.
template <int L, int P, int EXPERT, bool SLICE_M>
__global__ __launch_bounds__(256, 3) void expert_fused(
    const unsigned short* __restrict__ A,   // x bf16 [128*L, 512]
    const unsigned short* __restrict__ Wf,  // [P*512, 512] bf16
    const float* __restrict__ bf,           // [P*512]
    const float* __restrict__ gates, const int* __restrict__ bidx,
    const int* __restrict__ eidx, float* __restrict__ out, int ebase) {
  __shared__ __align__(16) char lds[32768];
  constexpr int TM = L;          // tiles along M (128 rows each; M = 128*L)
  constexpr int TN = 4 * P;      // tiles along N (128 cols each; N = 512*P)
  int bid = blockIdx.x;          // 1344 = 8 * 168, exact
  int xcd = bid & 7, pos = bid >> 3;
  int lin = xcd * (TM * TN / 8) + pos;
  int tileM, tileN;
  if (SLICE_M) { tileM = lin / TN; tileN = lin % TN; }  // chunk = tileM slice x all tileN
  else         { tileN = lin / TM; tileM = lin % TM; }  // chunk = tileN slice x all tileM

  int tid = threadIdx.x;
  int lane = tid & 63, w = tid >> 6;
  int wr0 = (w >> 1) * 64, wc0 = (w & 1) * 64;
  const unsigned short* Ag = A + (size_t)tileM * 128 * KDIM;
  const unsigned short* Bg = Wf + (size_t)tileN * 128 * KDIM;
  f32x4 acc[4][4] = {};
  gemm128_k512(Ag, Bg, lds, tid, acc);

  int j = tileN >> 2;
  int obase = (tileN & 3) * 128;
  float bv[4];
  int ocol[4];
#pragma unroll
  for (int fj = 0; fj < 4; ++fj) {
    ocol[fj] = obase + wc0 + fj * 16 + (lane & 15);
    bv[fj] = bf[(j << 9) + ocol[fj]];
  }
#pragma unroll
  for (int fi = 0; fi < 4; ++fi) {
    int m0 = tileM * 128 + wr0 + fi * 16 + (lane >> 4) * 4;
    int n = m0 / L, li = m0 - n * L;
    float* rp[4]; float gg[4]; bool fst[4];
#pragma unroll
    for (int r = 0; r < 4; ++r) {
      if (li == L) { li = 0; ++n; }
      int b = bidx[ebase + n];
      gg[r] = gates[b * 4 + eidx[ebase + n]];
      rp[r] = out + ((size_t)b * 336 + li * P + j) * 512;
      // first writer: E0 always; E1/E2 iff b%4==EXPERT; E3 never (b%4==3's first is E0!)
      fst[r] = (EXPERT == 0) || (EXPERT != 3 && (b & 3) == EXPERT);
      ++li;
    }
    float old[4][4];
    if (EXPERT != 0) {  // batch the RMW loads: up to 16 issued together, one latency exposure
#pragma unroll
      for (int r = 0; r < 4; ++r)
        if (!fst[r])
#pragma unroll
          for (int fj = 0; fj < 4; ++fj) old[r][fj] = rp[r][ocol[fj]];
    }
#pragma unroll
    for (int r = 0; r < 4; ++r)
#pragma unroll
      for (int fj = 0; fj < 4; ++fj) {
        float v = gg[r] * (acc[fi][fj][r] + bv[fj]);
        if (EXPERT != 0 && !fst[r]) v += old[r][fj];
        rp[r][ocol[fj]] = v;
      }
  }
}

extern "C" void kernel_launch(void* const* d_in, const int* in_sizes, int n_in,
                              void* d_out, int out_size, void* d_ws, size_t ws_size,
                              hipStream_t stream) {
  const float* xs[4]   = {(const float*)d_in[0], (const float*)d_in[3], (const float*)d_in[6], (const float*)d_in[9]};
  const float* Wfp[4]  = {(const float*)d_in[1], (const float*)d_in[4], (const float*)d_in[7], (const float*)d_in[10]};
  const float* bias[4] = {(const float*)d_in[2], (const float*)d_in[5], (const float*)d_in[8], (const float*)d_in[11]};
  const float* gates = (const float*)d_in[12];
  const float* Wp    = (const float*)d_in[13];
  const float* bp    = (const float*)d_in[14];
  const int* bidx    = (const int*)d_in[15];
  const int* eidx    = (const int*)d_in[16];

  static const int xs_elems[4] = {5505024, 2752512, 1835008, 917504};
  static const int W_elems[4]  = {1048576, 2097152, 3145728, 6291456};

  unsigned short* w = (unsigned short*)d_ws;
  size_t off = 0;
  unsigned short* xsb[4]; unsigned short* WtB[4]; unsigned short* Wfb[4];
  for (int i = 0; i < 4; i++) { xsb[i] = w + off; off += xs_elems[i]; }
  for (int i = 0; i < 4; i++) { WtB[i] = w + off; off += W_elems[i]; }
  for (int i = 0; i < 4; i++) { Wfb[i] = w + off; off += W_elems[i]; }
  unsigned short* Wpb = w + off; off += 262144;
  float* bfused = (float*)(w + off);  // 48*512 floats

  // --- prep: 4 launches ---
  CvtArgs ca = {xs[0], xs[1], xs[2], xs[3], Wp, xsb[0], xsb[1], xsb[2], xsb[3], Wpb};
  cvt_multi<<<5504, 256, 0, stream>>>(ca);

  TpArgs ta = {Wfp[0], Wfp[1], Wfp[2], Wfp[3], WtB[0], WtB[1], WtB[2], WtB[3]};
  transpose_all<<<3072, 256, 0, stream>>>(ta);

  FuseArgs fa = {WtB[0], WtB[1], WtB[2], WtB[3], Wfb[0], Wfb[1], Wfb[2], Wfb[3]};
  fuse_all<<<768, 256, 0, stream>>>(Wpb, fa);

  BiasArgs ba = {bias[0], bias[1], bias[2], bias[3]};
  bias_all<<<48, 256, 0, stream>>>(Wp, ba, bp, bfused);

  // --- fused expert GEMM + gated scatter-combine (no memset, no atomics) ---
  // SLICE_M when A-panel (L*131KB) > B-panel (4P*131KB): e0,e1 true; e2,e3 false.
  expert_fused<84, 4, 0, true ><<<1344, 256, 0, stream>>>(xsb[0], Wfb[0], bfused + 0 * 512,  gates, bidx, eidx, (float*)d_out, 0);
  expert_fused<42, 8, 1, true ><<<1344, 256, 0, stream>>>(xsb[1], Wfb[1], bfused + 4 * 512,  gates, bidx, eidx, (float*)d_out, 128);
  expert_fused<28, 12, 2, false><<<1344, 256, 0, stream>>>(xsb[2], Wfb[2], bfused + 12 * 512, gates, bidx, eidx, (float*)d_out, 256);
  expert_fused<14, 24, 3, false><<<1344, 256, 0, stream>>>(xsb[3], Wfb[3], bfused + 24 * 512, gates, bidx, eidx, (float*)d_out, 384);
}

// Round 7
// 260.880 us; speedup vs baseline: 1.4500x; 1.0487x over previous
//
#include <hip/hip_runtime.h>
#include <stdint.h>

typedef __bf16 bf16_t;
typedef bf16_t bf16x8 __attribute__((ext_vector_type(8)));
typedef float f32x4 __attribute__((ext_vector_type(4)));
typedef unsigned short u16x8 __attribute__((ext_vector_type(8)));

#define KDIM 512

__device__ __forceinline__ unsigned short f2bf(float f) {
  unsigned int u = __float_as_uint(f);
  u = (u + 0x7FFFu + ((u >> 16) & 1u)) >> 16;
  return (unsigned short)u;
}

// ================= merged fp32->bf16 conversion (5 segments, 8 elems/thread) =================
struct CvtArgs {
  const float *s0, *s1, *s2, *s3, *s4;
  unsigned short *d0, *d1, *d2, *d3, *d4;
};
__device__ __forceinline__ void cvt8(const float* s, unsigned short* d, int i) {
  const float4* sp = (const float4*)s;
  float4 a = sp[2 * (size_t)i], b = sp[2 * (size_t)i + 1];
  u16x8 r;
  r[0] = f2bf(a.x); r[1] = f2bf(a.y); r[2] = f2bf(a.z); r[3] = f2bf(a.w);
  r[4] = f2bf(b.x); r[5] = f2bf(b.y); r[6] = f2bf(b.z); r[7] = f2bf(b.w);
  *(u16x8*)(d + (size_t)8 * i) = r;
}
__global__ void cvt_multi(CvtArgs a) {
  int i = blockIdx.x * blockDim.x + threadIdx.x;
  if (i < 688128)       cvt8(a.s0, a.d0, i);
  else if (i < 1032192) cvt8(a.s1, a.d1, i - 688128);
  else if (i < 1261568) cvt8(a.s2, a.d2, i - 1032192);
  else if (i < 1376256) cvt8(a.s3, a.d3, i - 1261568);
  else                  cvt8(a.s4, a.d4, i - 1376256);
}

// ================= merged transpose+cvt: W[p*512,512] fp32 -> WtB[p][512 d][512 e] bf16 =========
struct TpArgs {
  const float *w0, *w1, *w2, *w3;
  unsigned short *t0, *t1, *t2, *t3;
};
__global__ __launch_bounds__(256) void transpose_all(TpArgs a) {
  __shared__ float tile[64][65];
  int bid = blockIdx.x;
  int e, base, P;
  if (bid < 256)       { e = 0; base = 0;    P = 4; }
  else if (bid < 768)  { e = 1; base = 256;  P = 8; }
  else if (bid < 1536) { e = 2; base = 768;  P = 12; }
  else                 { e = 3; base = 1536; P = 24; }
  const float* W = e == 0 ? a.w0 : e == 1 ? a.w1 : e == 2 ? a.w2 : a.w3;
  unsigned short* Wt = e == 0 ? a.t0 : e == 1 ? a.t1 : e == 2 ? a.t2 : a.t3;
  int r = bid - base;
  int qb = r % (P * 8), db = r / (P * 8);
  int q0 = qb * 64, d0 = db * 64;
  int t = threadIdx.x;
  int c = t & 63, r4 = t >> 6;
#pragma unroll
  for (int i = 0; i < 16; ++i) {
    int row = r4 + i * 4;
    tile[row][c] = W[(size_t)(q0 + row) * 512 + d0 + c];
  }
  __syncthreads();
  int j = q0 >> 9, e0 = q0 & 511;
  size_t obase = (size_t)j * 262144 + (size_t)d0 * 512 + e0;
#pragma unroll
  for (int i = 0; i < 16; ++i) {
    int dd = r4 + i * 4;
    Wt[obase + (size_t)dd * 512 + c] = f2bf(tile[c][dd]);
  }
}

// ================= merged fused bias: bf[jg*512+o] = Wp[o,:]@b_e[jl*512:]+bp[o] ================
struct BiasArgs { const float *b0, *b1, *b2, *b3; };
__global__ void bias_all(const float* __restrict__ Wp, BiasArgs a,
                         const float* __restrict__ bp, float* __restrict__ bf) {
  int jg = blockIdx.x;  // 0..47
  int e, base;
  if (jg < 4)       { e = 0; base = 0; }
  else if (jg < 12) { e = 1; base = 4; }
  else if (jg < 24) { e = 2; base = 12; }
  else              { e = 3; base = 24; }
  const float* b = e == 0 ? a.b0 : e == 1 ? a.b1 : e == 2 ? a.b2 : a.b3;
  int jl = jg - base;
  for (int o = threadIdx.x; o < 512; o += blockDim.x) {
    float s = bp[o];
    const float* wr = Wp + (size_t)o * 512;
    const float* br = b + (size_t)jl * 512;
    for (int ee = 0; ee < 512; ++ee) s += wr[ee] * br[ee];
    bf[(size_t)jg * 512 + o] = s;
  }
}

// ================= async global->LDS helpers ==================================================
__device__ __forceinline__ void gload_lds16(const unsigned short* g, unsigned short* l) {
  __builtin_amdgcn_global_load_lds(
      (const __attribute__((address_space(1))) void*)g,
      (__attribute__((address_space(3))) void*)l, 16, 0, 0);
}

// ---- stage a 128x32 bf16 tile (8 KB): LDS dest linear, global source chunk-swizzled ----
// LDS slot (row, sc) holds global 16B-chunk (sc ^ ((row>>1)&3)) of that row (rule #21).
// 2 gload_lds per thread => 2 vmcnt units/wave; A+B tile = 4 units.
__device__ __forceinline__ void stage32(const unsigned short* __restrict__ g,
                                        char* ldsOp, int tid, int kt) {
  int rlo = tid >> 2;
  int c = (tid & 3) ^ ((tid >> 3) & 3);
#pragma unroll
  for (int i = 0; i < 2; ++i) {
    int row = i * 64 + rlo;
    gload_lds16(g + (size_t)row * KDIM + kt * 32 + c * 8,
                (unsigned short*)(ldsOp + i * 4096 + tid * 16));
  }
}
// swizzled fragment read: global chunk c16 of row r lives at slot (c16 ^ ((r>>1)&3))
__device__ __forceinline__ bf16x8 lds_frag32(const char* op, int r, int c16) {
  return *(const bf16x8*)(op + r * 64 + ((c16 ^ ((r >> 1) & 3)) << 4));
}

// ================= 128x128 bf16 MFMA core, BK=32, 3-slot ring, counted vmcnt ==================
// 256 threads = 4 waves (2x2); per-wave 64x64 -> acc[4][4].  48 KiB LDS -> 3 blocks/CU.
// Slot k%3 holds K-tile k (A 8KB @+0, B 8KB @+8192; slot stride 16384).
// Pipeline: prologue stages tiles 0,1; iter s waits vmcnt(4) (own tile-s loads done, tile s+1
// stays in flight), barrier publishes all waves' staging, then stages tile s+2 into slot
// (s-1)%3 (all reads of it completed before this barrier), reads frags, 16 MFMA.
// Raw asm wait+barrier avoids __syncthreads' implicit vmcnt(0) drain — the R6 bottleneck.
__device__ __forceinline__ void gemm128_k512(
    const unsigned short* __restrict__ Ag, const unsigned short* __restrict__ Bg,
    char* lds, int tid, f32x4 acc[4][4]) {
  int lane = tid & 63, w = tid >> 6;
  int wr0 = (w >> 1) * 64, wc0 = (w & 1) * 64;
  int c16 = lane >> 4, rl = lane & 15;
  stage32(Ag, lds, tid, 0);
  stage32(Bg, lds + 8192, tid, 0);
  stage32(Ag, lds + 16384, tid, 1);
  stage32(Bg, lds + 16384 + 8192, tid, 1);
#pragma unroll
  for (int s = 0; s < 16; ++s) {
    if (s < 15) asm volatile("s_waitcnt vmcnt(4)\n\ts_barrier" ::: "memory");
    else        asm volatile("s_waitcnt vmcnt(0)\n\ts_barrier" ::: "memory");
    char* cur = lds + (s % 3) * 16384;
    if (s + 2 < 16) {  // issue next+1 stage first: overlaps ds_read + MFMA below
      char* nxt = lds + ((s + 2) % 3) * 16384;
      stage32(Ag, nxt, tid, s + 2);
      stage32(Bg, nxt + 8192, tid, s + 2);
    }
    bf16x8 av[4], bv[4];
#pragma unroll
    for (int f = 0; f < 4; ++f) {
      av[f] = lds_frag32(cur, wr0 + f * 16 + rl, c16);
      bv[f] = lds_frag32(cur + 8192, wc0 + f * 16 + rl, c16);
    }
    __builtin_amdgcn_s_setprio(1);
#pragma unroll
    for (int fi = 0; fi < 4; ++fi)
#pragma unroll
      for (int fj = 0; fj < 4; ++fj)
        acc[fi][fj] = __builtin_amdgcn_mfma_f32_16x16x32_bf16(av[fi], bv[fj], acc[fi][fj], 0, 0, 0);
    __builtin_amdgcn_s_setprio(0);
  }
}

// ================= merged weight-fuse GEMM: Wf[(j,o),d] = sum_e Wp[o,e]*WtB[j][d][e] ===========
struct FuseArgs {
  const unsigned short *wt0, *wt1, *wt2, *wt3;
  unsigned short *wf0, *wf1, *wf2, *wf3;
};
__global__ __launch_bounds__(256, 3) void fuse_all(const unsigned short* __restrict__ Wpb, FuseArgs a) {
  __shared__ __align__(16) char lds[49152];
  int bid = blockIdx.x;
  int e, base, P;
  if (bid < 64)       { e = 0; base = 0;   P = 4; }
  else if (bid < 192) { e = 1; base = 64;  P = 8; }
  else if (bid < 384) { e = 2; base = 192; P = 12; }
  else                { e = 3; base = 384; P = 24; }
  const unsigned short* WtB = e == 0 ? a.wt0 : e == 1 ? a.wt1 : e == 2 ? a.wt2 : a.wt3;
  unsigned short* Wf = e == 0 ? a.wf0 : e == 1 ? a.wf1 : e == 2 ? a.wf2 : a.wf3;
  int r = bid - base;
  int tileM = r % (4 * P), tileN = r / (4 * P);
  int tid = threadIdx.x;
  int lane = tid & 63, w = tid >> 6;
  int wr0 = (w >> 1) * 64, wc0 = (w & 1) * 64;
  int j = (tileM * 128) >> 9;
  const unsigned short* Ag = Wpb + (size_t)((tileM * 128) & 511) * 512;
  const unsigned short* Bg = WtB + (size_t)j * 262144 + (size_t)(tileN * 128) * 512;
  f32x4 acc[4][4] = {};
  gemm128_k512(Ag, Bg, lds, tid, acc);
#pragma unroll
  for (int fi = 0; fi < 4; ++fi)
#pragma unroll
    for (int fj = 0; fj < 4; ++fj) {
      int col = tileN * 128 + wc0 + fj * 16 + (lane & 15);
#pragma unroll
      for (int r2 = 0; r2 < 4; ++r2) {
        int m = tileM * 128 + wr0 + fi * 16 + (lane >> 4) * 4 + r2;
        Wf[(size_t)m * 512 + col] = f2bf(acc[fi][fj][r2]);
      }
    }
}

// ================= fused expert GEMM + gate + scatter-combine (4 serialized launches) ==========
// Routing: batch b -> experts {b%4, (b+1)%4}; first writer = min of the pair:
//   b%4==0 -> E0, 1 -> E1, 2 -> E2, 3 -> E0.
// => E0 always stores; E1 first iff b%4==1; E2 first iff b%4==2; E3 NEVER first (pure RMW).
// Plain RMW is race-free: one touch per element per kernel; the 4 expert kernels are
// stream-serialized.  (Do NOT merge these launches.)
// XCD-chunked swizzle: xcd = bid&7 owns a contiguous slice of the LARGER-operand tile dim
// x full range of the other -> per-XCD working set (~3-4.5 MB) stays L2-resident.
template <int L, int P, int EXPERT, bool SLICE_M>
__global__ __launch_bounds__(256, 3) void expert_fused(
    const unsigned short* __restrict__ A,   // x bf16 [128*L, 512]
    const unsigned short* __restrict__ Wf,  // [P*512, 512] bf16
    const float* __restrict__ bf,           // [P*512]
    const float* __restrict__ gates, const int* __restrict__ bidx,
    const int* __restrict__ eidx, float* __restrict__ out, int ebase) {
  __shared__ __align__(16) char lds[49152];
  constexpr int TM = L;          // tiles along M (128 rows each; M = 128*L)
  constexpr int TN = 4 * P;      // tiles along N (128 cols each; N = 512*P)
  int bid = blockIdx.x;          // 1344 = 8 * 168, exact
  int xcd = bid & 7, pos = bid >> 3;
  int lin = xcd * (TM * TN / 8) + pos;
  int tileM, tileN;
  if (SLICE_M) { tileM = lin / TN; tileN = lin % TN; }  // chunk = tileM slice x all tileN
  else         { tileN = lin / TM; tileM = lin % TM; }  // chunk = tileN slice x all tileM

  int tid = threadIdx.x;
  int lane = tid & 63, w = tid >> 6;
  int wr0 = (w >> 1) * 64, wc0 = (w & 1) * 64;
  const unsigned short* Ag = A + (size_t)tileM * 128 * KDIM;
  const unsigned short* Bg = Wf + (size_t)tileN * 128 * KDIM;
  f32x4 acc[4][4] = {};
  gemm128_k512(Ag, Bg, lds, tid, acc);

  int j = tileN >> 2;
  int obase = (tileN & 3) * 128;
  float bv[4];
  int ocol[4];
#pragma unroll
  for (int fj = 0; fj < 4; ++fj) {
    ocol[fj] = obase + wc0 + fj * 16 + (lane & 15);
    bv[fj] = bf[(j << 9) + ocol[fj]];
  }
#pragma unroll
  for (int fi = 0; fi < 4; ++fi) {
    int m0 = tileM * 128 + wr0 + fi * 16 + (lane >> 4) * 4;
    int n = m0 / L, li = m0 - n * L;
    float* rp[4]; float gg[4]; bool fst[4];
#pragma unroll
    for (int r = 0; r < 4; ++r) {
      if (li == L) { li = 0; ++n; }
      int b = bidx[ebase + n];
      gg[r] = gates[b * 4 + eidx[ebase + n]];
      rp[r] = out + ((size_t)b * 336 + li * P + j) * 512;
      // first writer: E0 always; E1/E2 iff b%4==EXPERT; E3 never (b%4==3's first is E0!)
      fst[r] = (EXPERT == 0) || (EXPERT != 3 && (b & 3) == EXPERT);
      ++li;
    }
    float old[4][4];
    if (EXPERT != 0) {  // batch the RMW loads: up to 16 issued together, one latency exposure
#pragma unroll
      for (int r = 0; r < 4; ++r)
        if (!fst[r])
#pragma unroll
          for (int fj = 0; fj < 4; ++fj) old[r][fj] = rp[r][ocol[fj]];
    }
#pragma unroll
    for (int r = 0; r < 4; ++r)
#pragma unroll
      for (int fj = 0; fj < 4; ++fj) {
        float v = gg[r] * (acc[fi][fj][r] + bv[fj]);
        if (EXPERT != 0 && !fst[r]) v += old[r][fj];
        rp[r][ocol[fj]] = v;
      }
  }
}

extern "C" void kernel_launch(void* const* d_in, const int* in_sizes, int n_in,
                              void* d_out, int out_size, void* d_ws, size_t ws_size,
                              hipStream_t stream) {
  const float* xs[4]   = {(const float*)d_in[0], (const float*)d_in[3], (const float*)d_in[6], (const float*)d_in[9]};
  const float* Wfp[4]  = {(const float*)d_in[1], (const float*)d_in[4], (const float*)d_in[7], (const float*)d_in[10]};
  const float* bias[4] = {(const float*)d_in[2], (const float*)d_in[5], (const float*)d_in[8], (const float*)d_in[11]};
  const float* gates = (const float*)d_in[12];
  const float* Wp    = (const float*)d_in[13];
  const float* bp    = (const float*)d_in[14];
  const int* bidx    = (const int*)d_in[15];
  const int* eidx    = (const int*)d_in[16];

  static const int xs_elems[4] = {5505024, 2752512, 1835008, 917504};
  static const int W_elems[4]  = {1048576, 2097152, 3145728, 6291456};

  unsigned short* w = (unsigned short*)d_ws;
  size_t off = 0;
  unsigned short* xsb[4]; unsigned short* WtB[4]; unsigned short* Wfb[4];
  for (int i = 0; i < 4; i++) { xsb[i] = w + off; off += xs_elems[i]; }
  for (int i = 0; i < 4; i++) { WtB[i] = w + off; off += W_elems[i]; }
  for (int i = 0; i < 4; i++) { Wfb[i] = w + off; off += W_elems[i]; }
  unsigned short* Wpb = w + off; off += 262144;
  float* bfused = (float*)(w + off);  // 48*512 floats

  // --- prep: 4 launches ---
  CvtArgs ca = {xs[0], xs[1], xs[2], xs[3], Wp, xsb[0], xsb[1], xsb[2], xsb[3], Wpb};
  cvt_multi<<<5504, 256, 0, stream>>>(ca);

  TpArgs ta = {Wfp[0], Wfp[1], Wfp[2], Wfp[3], WtB[0], WtB[1], WtB[2], WtB[3]};
  transpose_all<<<3072, 256, 0, stream>>>(ta);

  FuseArgs fa = {WtB[0], WtB[1], WtB[2], WtB[3], Wfb[0], Wfb[1], Wfb[2], Wfb[3]};
  fuse_all<<<768, 256, 0, stream>>>(Wpb, fa);

  BiasArgs ba = {bias[0], bias[1], bias[2], bias[3]};
  bias_all<<<48, 256, 0, stream>>>(Wp, ba, bp, bfused);

  // --- fused expert GEMM + gated scatter-combine (no memset, no atomics) ---
  // SLICE_M when A-panel (L*131KB) > B-panel (4P*131KB): e0,e1 true; e2,e3 false.
  expert_fused<84, 4, 0, true ><<<1344, 256, 0, stream>>>(xsb[0], Wfb[0], bfused + 0 * 512,  gates, bidx, eidx, (float*)d_out, 0);
  expert_fused<42, 8, 1, true ><<<1344, 256, 0, stream>>>(xsb[1], Wfb[1], bfused + 4 * 512,  gates, bidx, eidx, (float*)d_out, 128);
  expert_fused<28, 12, 2, false><<<1344, 256, 0, stream>>>(xsb[2], Wfb[2], bfused + 12 * 512, gates, bidx, eidx, (float*)d_out, 256);
  expert_fused<14, 24, 3, false><<<1344, 256, 0, stream>>>(xsb[3], Wfb[3], bfused + 24 * 512, gates, bidx, eidx, (float*)d_out, 384);
}